// Round 2
// baseline (828.921 us; speedup 1.0000x reference)
//
#include <hip/hip_runtime.h>

#define S 512
#define NB 8          // batch
#define KT 256        // k-tile per block
#define JT 32         // j-tile per staging round

// Copy the untouched region: out[b,r,c] = x[b,r,c] for r+c >= S.
__global__ __launch_bounds__(256) void tail_copy_kernel(const float* __restrict__ x,
                                                        float* __restrict__ out) {
  int idx = blockIdx.x * 256 + threadIdx.x;
  int c = idx & (S - 1);
  int r = (idx >> 9) & (S - 1);
  if (r + c >= S) out[idx] = x[idx];
}

// One block per (diagonal i, k-tile). Computes out[b, i-k, k] for k in tile.
// Diagonal index is XCD-swizzled: consecutive-i stripes of 16 land on one XCD
// (bx%8 round-robin assumption) so the 16-way line sharing of the x-gather and
// out-scatter is merged inside a single (non-coherent) per-XCD L2.
__global__ __launch_bounds__(256, 3) void diag_linear_kernel(const float* __restrict__ x,
                                                             const float* __restrict__ W,
                                                             const float* __restrict__ bias,
                                                             float* __restrict__ out) {
  // Wt: transposed W tile, 32 KB. Logical Wt[j][k]; the 16B chunk holding
  // k=4c..4c+3 of row j is stored at physical chunk (c ^ (j&7)) so that:
  //   - compute reads (lane l -> chunk l of row jl) are linear/conflict-free
  //   - transpose stores are only 4-way conflicted b32s
  // Reused as Racc[b][k] (8 KB) for the cross-wave reduction.
  __shared__ __align__(16) float WtBuf[JT * KT];
  // Dl[j][b]: gathered diagonal of x (16 KB).
  __shared__ __align__(16) float DlBuf[S * NB];

  // ---- XCD-aware diagonal swizzle (big diagonals first within each stripe) ----
  const int bx = (int)blockIdx.x;          // 0..511
  const int u  = bx >> 3;                  // 0..63
  const int xc = bx & 7;                   // assumed XCD (round-robin dispatch)
  const int i  = (S - 1) - ((u & 15) + 16 * (xc + 8 * (u >> 4)));
  const int k0 = (int)blockIdx.y * KT;
  if (k0 > i) return;                      // uniform exit, before any barrier

  const int tid  = threadIdx.x;
  const int wave = tid >> 6;
  const int lane = tid & 63;

  const int jend = (i + JT) & ~(JT - 1);   // roundup(i+1, JT)

  // ---- stage D: Dl[j][b] = x[b, j, i-j] for j<=i, else 0 (zero-fill padding) ----
  for (int idx = tid; idx < jend * NB; idx += 256) {
    const int j = idx >> 3;
    const int b = idx & 7;
    DlBuf[idx] = (j <= i) ? x[b * (S * S) + j * S + (i - j)] : 0.0f;
  }

  // accumulators: lane owns k_local = 4*lane + m, all 8 batches
  float acc[4][NB];
#pragma unroll
  for (int m = 0; m < 4; ++m)
#pragma unroll
    for (int b = 0; b < NB; ++b) acc[m][b] = 0.0f;

  // ---- coalesced W tile loader: pass p covers rows k_local in [32p, 32p+32),
  // 8 consecutive lanes read one contiguous 128 B row-chunk.
  const int kl_base = tid >> 3;            // 0..31 row-in-pass
  const int jb      = (tid & 7) << 2;      // j base: 0,4,...,28
  const float* Wdiag = W + (size_t)i * S * S;

  float4 v[8];
#define LOAD_TILE(J0)                                                          \
  {                                                                            \
    _Pragma("unroll")                                                          \
    for (int p = 0; p < 8; ++p) {                                              \
      const int k = k0 + (p << 5) + kl_base;                                   \
      v[p] = (k <= i) ? *(const float4*)(Wdiag + (size_t)k * S + (J0) + jb)    \
                      : make_float4(0.f, 0.f, 0.f, 0.f);                       \
    }                                                                          \
  }

  LOAD_TILE(0)

  for (int j0 = 0; j0 < jend; j0 += JT) {
    __syncthreads();                       // previous tile's compute done; Wt free
    // transpose + swizzle store: element (k_local, jb+q) -> row jb+q,
    // logical chunk c = k_local>>2, word w = k_local&3, phys chunk c^( (jb+q)&7 )
#pragma unroll
    for (int p = 0; p < 8; ++p) {
      const int kl = (p << 5) + kl_base;
      const int c  = kl >> 2;
      const int w  = kl & 3;
      const float e[4] = {v[p].x, v[p].y, v[p].z, v[p].w};
#pragma unroll
      for (int q = 0; q < 4; ++q) {
        const int j = jb + q;
        WtBuf[j * KT + (((c ^ (j & 7)) << 2) | w)] = e[q];
      }
    }
    // software pipeline: issue next tile's global loads before computing this one
    const int jn = j0 + JT;
    if (jn < jend) LOAD_TILE(jn)
    __syncthreads();                       // Wt (and Dl on first iter) visible

    // compute: wave handles j_local in [8*wave, 8*wave+8)
#pragma unroll
    for (int uu = 0; uu < 8; ++uu) {
      const int jl = (wave << 3) + uu;
      // lane l reads logical chunk l of row jl -> physical chunk l ^ (jl&7)
      const float4 wv = *(const float4*)&WtBuf[jl * KT + ((lane ^ (jl & 7)) << 2)];
      const float4 dA = *(const float4*)&DlBuf[(j0 + jl) * NB];      // broadcast
      const float4 dB = *(const float4*)&DlBuf[(j0 + jl) * NB + 4];  // broadcast
      const float wm[4] = {wv.x, wv.y, wv.z, wv.w};
#pragma unroll
      for (int m = 0; m < 4; ++m) {
        acc[m][0] = fmaf(wm[m], dA.x, acc[m][0]);
        acc[m][1] = fmaf(wm[m], dA.y, acc[m][1]);
        acc[m][2] = fmaf(wm[m], dA.z, acc[m][2]);
        acc[m][3] = fmaf(wm[m], dA.w, acc[m][3]);
        acc[m][4] = fmaf(wm[m], dB.x, acc[m][4]);
        acc[m][5] = fmaf(wm[m], dB.y, acc[m][5]);
        acc[m][6] = fmaf(wm[m], dB.z, acc[m][6]);
        acc[m][7] = fmaf(wm[m], dB.w, acc[m][7]);
      }
    }
  }

  __syncthreads();                         // all compute done; Wt reusable as Racc
  float* Racc = WtBuf;                     // Racc[b*KT + k_local]

  // cross-wave reduction (waves split j, so each holds partials for all k)
  for (int w = 0; w < 4; ++w) {
    if (wave == w) {
#pragma unroll
      for (int b = 0; b < NB; ++b) {
        float4* p = (float4*)&Racc[b * KT + (lane << 2)];  // conflict-free b128
        float4 cur = make_float4(acc[0][b], acc[1][b], acc[2][b], acc[3][b]);
        if (w != 0) {
          float4 old = *p;
          cur.x += old.x; cur.y += old.y; cur.z += old.z; cur.w += old.w;
        }
        *p = cur;
      }
    }
    __syncthreads();
  }

  // epilogue: bias + scatter out[b, i-k, k]
  const int k = k0 + tid;
  if (k <= i) {
    const float bv = bias[i * S + k];
    const int r = i - k;
#pragma unroll
    for (int b = 0; b < NB; ++b)
      out[b * (S * S) + r * S + k] = Racc[b * KT + tid] + bv;
  }
}

extern "C" void kernel_launch(void* const* d_in, const int* in_sizes, int n_in,
                              void* d_out, int out_size, void* d_ws, size_t ws_size,
                              hipStream_t stream) {
  const float* x    = (const float*)d_in[0];
  const float* W    = (const float*)d_in[1];
  const float* bias = (const float*)d_in[2];
  float* out = (float*)d_out;

  (void)d_ws; (void)ws_size; (void)in_sizes; (void)n_in; (void)out_size;

  tail_copy_kernel<<<dim3((NB * S * S) / 256), 256, 0, stream>>>(x, out);
  diag_linear_kernel<<<dim3(S, 2), 256, 0, stream>>>(x, W, bias, out);
}

// Round 3
// 716.893 us; speedup vs baseline: 1.1563x; 1.1563x over previous
//
#include <hip/hip_runtime.h>

#define S 512
#define NB 8          // batch
#define KT 256        // k-tile per block
#define JT 32         // j-tile per staging round

// Copy the untouched region: out[b,r,c] = x[b,r,c] for r+c >= S.
__global__ __launch_bounds__(256) void tail_copy_kernel(const float* __restrict__ x,
                                                        float* __restrict__ out) {
  int idx = blockIdx.x * 256 + threadIdx.x;
  int c = idx & (S - 1);
  int r = (idx >> 9) & (S - 1);
  if (r + c >= S) out[idx] = x[idx];
}

// One block per (diagonal i, k-tile). Computes out[b, i-k, k] for k in tile.
// i is XCD-swizzled: stripes of 16 consecutive diagonals land on one XCD
// (bx%8 round-robin assumption) so the 16-way out-line/x-line sharing across
// neighboring diagonals merges inside a single per-XCD L2.
// W staging: per-thread row streaming (R1 loader) with a 2-tile-deep VGPR
// prefetch pipeline -> 16 outstanding dwordx4/thread; loads stay in flight
// across __syncthreads (VGPR staging needs no vmcnt(0) drain at barriers).
__global__ __launch_bounds__(256, 3) void diag_linear_kernel(const float* __restrict__ x,
                                                             const float* __restrict__ W,
                                                             const float* __restrict__ bias,
                                                             float* __restrict__ out) {
  // Wt[j][k]: transposed W tile (32 KB). Reused as Racc[b][k] (8 KB) at the end.
  __shared__ __align__(16) float WtBuf[JT * KT];
  // Dl[j][b]: gathered diagonal of x (16 KB).
  __shared__ __align__(16) float DlBuf[S * NB];

  // ---- XCD-aware diagonal swizzle (big diagonals first within each stripe) ----
  const int bx = (int)blockIdx.x;          // 0..511
  const int u  = bx >> 3;                  // 0..63
  const int xc = bx & 7;                   // assumed XCD (round-robin dispatch)
  const int i  = (S - 1) - ((u & 15) + 16 * (xc + 8 * (u >> 4)));
  const int k0 = (int)blockIdx.y * KT;
  if (k0 > i) return;                      // uniform exit, before any barrier

  const int tid  = threadIdx.x;
  const int wave = tid >> 6;
  const int lane = tid & 63;

  const int jend = (i + JT) & ~(JT - 1);   // roundup(i+1, JT)
  const int T    = jend >> 5;              // number of j-tiles (>=1)

  // ---- stage D: Dl[j][b] = x[b, j, i-j] for j<=i, else 0 ----
  for (int idx = tid; idx < jend * NB; idx += 256) {
    const int j = idx >> 3;
    const int b = idx & 7;
    DlBuf[idx] = (j <= i) ? x[b * (S * S) + j * S + (i - j)] : 0.0f;
  }

  // accumulators: lane owns k_local = 4*lane + m, all 8 batches
  float acc[4][NB];
#pragma unroll
  for (int m = 0; m < 4; ++m)
#pragma unroll
    for (int b = 0; b < NB; ++b) acc[m][b] = 0.0f;

  const int  k       = k0 + tid;           // this thread's W row
  const bool krow_ok = (k <= i);           // rows k>i are all-zero: skip HBM reads
  const float* wrow  = W + ((size_t)i * S + k) * S;

  // ---- 2-deep prefetch pipeline ----
  // Note: W[i,k,j]=0 in memory for j>i, so tiles may read up to jend<=512
  // without j-masking; only k>i rows are skipped (those ARE worth the BW).
  float4 v[2][8];
  if (!krow_ok) {
#pragma unroll
    for (int g = 0; g < 2; ++g)
#pragma unroll
      for (int q = 0; q < 8; ++q) v[g][q] = make_float4(0.f, 0.f, 0.f, 0.f);
  }

#define LOAD_GRP(g, J0)                                                        \
  if (krow_ok) {                                                               \
    _Pragma("unroll")                                                          \
    for (int q = 0; q < 8; ++q)                                                \
      v[g][q] = *(const float4*)(wrow + (J0) + 4 * q);                         \
  }

  LOAD_GRP(0, 0)
  if (T > 1) LOAD_GRP(1, 32)

  for (int t = 0; t < T; ++t) {
    const int pb = t & 1;
    const int j0 = t << 5;
    __syncthreads();                       // previous tile's compute done; Wt free
    // store oldest group: compiler waits vmcnt for this group only,
    // the other group's 8 loads stay in flight
    {
      const float4* vv = v[pb];
#pragma unroll
      for (int q = 0; q < 8; ++q) {
        WtBuf[(4 * q + 0) * KT + tid] = vv[q].x;
        WtBuf[(4 * q + 1) * KT + tid] = vv[q].y;
        WtBuf[(4 * q + 2) * KT + tid] = vv[q].z;
        WtBuf[(4 * q + 3) * KT + tid] = vv[q].w;
      }
    }
    // refill this group's slot with tile t+2
    const int tn = t + 2;
    if (tn < T) LOAD_GRP(pb, tn << 5)
    __syncthreads();                       // Wt (and Dl on first iter) visible

    // compute: wave handles j_local in [8*wave, 8*wave+8)
#pragma unroll
    for (int uu = 0; uu < 8; ++uu) {
      const int jl = (wave << 3) + uu;
      const float4 wv = *(const float4*)&WtBuf[jl * KT + (lane << 2)]; // conflict-free b128
      const float4 dA = *(const float4*)&DlBuf[(j0 + jl) * NB];        // broadcast
      const float4 dB = *(const float4*)&DlBuf[(j0 + jl) * NB + 4];    // broadcast
      const float wm[4] = {wv.x, wv.y, wv.z, wv.w};
#pragma unroll
      for (int m = 0; m < 4; ++m) {
        acc[m][0] = fmaf(wm[m], dA.x, acc[m][0]);
        acc[m][1] = fmaf(wm[m], dA.y, acc[m][1]);
        acc[m][2] = fmaf(wm[m], dA.z, acc[m][2]);
        acc[m][3] = fmaf(wm[m], dA.w, acc[m][3]);
        acc[m][4] = fmaf(wm[m], dB.x, acc[m][4]);
        acc[m][5] = fmaf(wm[m], dB.y, acc[m][5]);
        acc[m][6] = fmaf(wm[m], dB.z, acc[m][6]);
        acc[m][7] = fmaf(wm[m], dB.w, acc[m][7]);
      }
    }
  }

  __syncthreads();                         // all compute done; Wt reusable as Racc
  float* Racc = WtBuf;                     // Racc[b*KT + k_local]

  // cross-wave reduction (waves split j, so each holds partials for all k)
  for (int w = 0; w < 4; ++w) {
    if (wave == w) {
#pragma unroll
      for (int b = 0; b < NB; ++b) {
        float4* p = (float4*)&Racc[b * KT + (lane << 2)];  // conflict-free b128
        float4 cur = make_float4(acc[0][b], acc[1][b], acc[2][b], acc[3][b]);
        if (w != 0) {
          float4 old = *p;
          cur.x += old.x; cur.y += old.y; cur.z += old.z; cur.w += old.w;
        }
        *p = cur;
      }
    }
    __syncthreads();
  }

  // epilogue: bias + scatter out[b, i-k, k]
  if (krow_ok) {
    const float bv = bias[i * S + k];
    const int r = i - k;
#pragma unroll
    for (int b = 0; b < NB; ++b)
      out[b * (S * S) + r * S + k] = Racc[b * KT + tid] + bv;
  }
}

extern "C" void kernel_launch(void* const* d_in, const int* in_sizes, int n_in,
                              void* d_out, int out_size, void* d_ws, size_t ws_size,
                              hipStream_t stream) {
  const float* x    = (const float*)d_in[0];
  const float* W    = (const float*)d_in[1];
  const float* bias = (const float*)d_in[2];
  float* out = (float*)d_out;

  (void)d_ws; (void)ws_size; (void)in_sizes; (void)n_in; (void)out_size;

  tail_copy_kernel<<<dim3((NB * S * S) / 256), 256, 0, stream>>>(x, out);
  diag_linear_kernel<<<dim3(S, 2), 256, 0, stream>>>(x, W, bias, out);
}

// Round 4
// 701.546 us; speedup vs baseline: 1.1816x; 1.0219x over previous
//
#include <hip/hip_runtime.h>

#define S 512
#define NB 8          // batch
#define KT 128        // k-tile per block (128 for load balance across CUs)
#define JT 32         // j-tile per staging round

// Copy the untouched region: out[b,r,c] = x[b,r,c] for r+c >= S.
__global__ __launch_bounds__(256) void tail_copy_kernel(const float* __restrict__ x,
                                                        float* __restrict__ out) {
  int idx = blockIdx.x * 256 + threadIdx.x;
  int c = idx & (S - 1);
  int r = (idx >> 9) & (S - 1);
  if (r + c >= S) out[idx] = x[idx];
}

// One block per (diagonal i, k-tile of 128). Computes out[b, i-k, k] for k in tile.
// i = 511 - bx: biggest diagonals dispatch first so the scheduler backfills small
// blocks onto early-finishing CUs (LPT-style balance; KT=128 keeps max block at
// 256 KB of W vs the 0.73 MB/CU average). No XCD swizzle: it concentrated the
// largest diagonals on one XCD (R2/R3 regressions).
// W staging: thread owns half a row per tile; 2-tile-deep VGPR prefetch so loads
// stay in flight across __syncthreads (no vmcnt(0) drain needed for VGPR staging).
__global__ __launch_bounds__(256, 4) void diag_linear_kernel(const float* __restrict__ x,
                                                             const float* __restrict__ W,
                                                             const float* __restrict__ bias,
                                                             float* __restrict__ out) {
  // Wt[j][k]: transposed W tile, 32 x 128 floats = 16 KB. Reused as Racc[b][k] at end.
  __shared__ __align__(16) float WtBuf[JT * KT];
  // Dl[j][b]: gathered diagonal of x (16 KB).
  __shared__ __align__(16) float DlBuf[S * NB];

  const int i  = (S - 1) - (int)blockIdx.x;  // big diagonals first
  const int k0 = (int)blockIdx.y * KT;
  if (k0 > i) return;                        // uniform exit, before any barrier

  const int tid  = threadIdx.x;
  const int wave = tid >> 6;
  const int lane = tid & 63;

  const int jend = (i + JT) & ~(JT - 1);     // roundup(i+1, JT)
  const int T    = jend >> 5;                // number of j-tiles (>=1)

  // ---- stage D: Dl[j][b] = x[b, j, i-j] for j<=i, else 0 ----
  for (int idx = tid; idx < jend * NB; idx += 256) {
    const int j = idx >> 3;
    const int b = idx & 7;
    DlBuf[idx] = (j <= i) ? x[b * (S * S) + j * S + (i - j)] : 0.0f;
  }

  // ---- loader role: thread owns row kl_r, half h of each 32-float j-tile ----
  const int kl_r = tid & (KT - 1);           // 0..127
  const int h    = tid >> 7;                 // 0 or 1: which 16-float half
  const int  k_r     = k0 + kl_r;
  const bool krow_ok = (k_r <= i);           // rows k>i are all-zero: skip HBM reads
  const float* wrow  = W + ((size_t)i * S + k_r) * S + (h << 4);

  // accumulators: lane owns k_local = 2*lane..2*lane+1, all 8 batches
  float acc[2][NB];
#pragma unroll
  for (int m = 0; m < 2; ++m)
#pragma unroll
    for (int b = 0; b < NB; ++b) acc[m][b] = 0.0f;

  // ---- 2-deep prefetch pipeline (4 dwordx4 per thread per tile) ----
  // W[i,k,j]=0 in memory for j>i, so tiles may read up to jend<=512 unmasked.
  float4 v[2][4];
  if (!krow_ok) {
#pragma unroll
    for (int g = 0; g < 2; ++g)
#pragma unroll
      for (int q = 0; q < 4; ++q) v[g][q] = make_float4(0.f, 0.f, 0.f, 0.f);
  }

#define LOAD_GRP(g, J0)                                                        \
  if (krow_ok) {                                                               \
    _Pragma("unroll")                                                          \
    for (int q = 0; q < 4; ++q)                                                \
      v[g][q] = *(const float4*)(wrow + (J0) + 4 * q);                         \
  }

  LOAD_GRP(0, 0)
  if (T > 1) LOAD_GRP(1, 32)

  for (int t = 0; t < T; ++t) {
    const int pb = t & 1;
    const int j0 = t << 5;
    __syncthreads();                         // previous tile's compute done; Wt free
    // transpose store: element (kl_r, j_local=16h+4q+e) -> Wt[j_local][kl_r]
    // per-(q,e) store: lanes hold consecutive kl_r -> 2-way bank alias (free)
    {
      const float4* vv = v[pb];
#pragma unroll
      for (int q = 0; q < 4; ++q) {
        const int jl = (h << 4) + (q << 2);
        WtBuf[(jl + 0) * KT + kl_r] = vv[q].x;
        WtBuf[(jl + 1) * KT + kl_r] = vv[q].y;
        WtBuf[(jl + 2) * KT + kl_r] = vv[q].z;
        WtBuf[(jl + 3) * KT + kl_r] = vv[q].w;
      }
    }
    // refill this group's slot with tile t+2
    const int tn = t + 2;
    if (tn < T) LOAD_GRP(pb, tn << 5)
    __syncthreads();                         // Wt (and Dl on first iter) visible

    // compute: wave handles j_local in [8*wave, 8*wave+8); lane owns 2 k
#pragma unroll
    for (int uu = 0; uu < 8; ++uu) {
      const int jl = (wave << 3) + uu;
      const float2 wv = *(const float2*)&WtBuf[jl * KT + (lane << 1)]; // b64
      const float4 dA = *(const float4*)&DlBuf[(j0 + jl) * NB];        // broadcast
      const float4 dB = *(const float4*)&DlBuf[(j0 + jl) * NB + 4];    // broadcast
      const float wm[2] = {wv.x, wv.y};
#pragma unroll
      for (int m = 0; m < 2; ++m) {
        acc[m][0] = fmaf(wm[m], dA.x, acc[m][0]);
        acc[m][1] = fmaf(wm[m], dA.y, acc[m][1]);
        acc[m][2] = fmaf(wm[m], dA.z, acc[m][2]);
        acc[m][3] = fmaf(wm[m], dA.w, acc[m][3]);
        acc[m][4] = fmaf(wm[m], dB.x, acc[m][4]);
        acc[m][5] = fmaf(wm[m], dB.y, acc[m][5]);
        acc[m][6] = fmaf(wm[m], dB.z, acc[m][6]);
        acc[m][7] = fmaf(wm[m], dB.w, acc[m][7]);
      }
    }
  }

  __syncthreads();                           // all compute done; Wt reusable as Racc
  float* Racc = WtBuf;                       // Racc[b*KT + k_local]

  // cross-wave reduction (waves split j, so each holds partials for all k)
  for (int w = 0; w < 4; ++w) {
    if (wave == w) {
#pragma unroll
      for (int b = 0; b < NB; ++b) {
        float2* p = (float2*)&Racc[b * KT + (lane << 1)];
        float2 cur = make_float2(acc[0][b], acc[1][b]);
        if (w != 0) {
          float2 old = *p;
          cur.x += old.x; cur.y += old.y;
        }
        *p = cur;
      }
    }
    __syncthreads();
  }

  // epilogue: bias + scatter out[b, i-k, k]; thread handles (kl_r, 4 batches)
  {
    const int k = k0 + kl_r;
    if (k <= i) {
      const float bv = bias[i * S + k];
      const int r = i - k;
#pragma unroll
      for (int bq = 0; bq < 4; ++bq) {
        const int b = (h << 2) + bq;
        out[b * (S * S) + r * S + k] = Racc[b * KT + kl_r] + bv;
      }
    }
  }
}

extern "C" void kernel_launch(void* const* d_in, const int* in_sizes, int n_in,
                              void* d_out, int out_size, void* d_ws, size_t ws_size,
                              hipStream_t stream) {
  const float* x    = (const float*)d_in[0];
  const float* W    = (const float*)d_in[1];
  const float* bias = (const float*)d_in[2];
  float* out = (float*)d_out;

  (void)d_ws; (void)ws_size; (void)in_sizes; (void)n_in; (void)out_size;

  tail_copy_kernel<<<dim3((NB * S * S) / 256), 256, 0, stream>>>(x, out);
  diag_linear_kernel<<<dim3(S, S / KT), 256, 0, stream>>>(x, W, bias, out);
}